// Round 15
// baseline (161.971 us; speedup 1.0000x reference)
//
#include <hip/hip_runtime.h>

#define BATCH 1024
#define SEQ   200
#define EMB   128
#define VOCAB 100000

typedef __attribute__((ext_vector_type(8))) short short8;
typedef __attribute__((ext_vector_type(4))) float f32x4;
typedef _Float16 hh2 __attribute__((ext_vector_type(2)));

__device__ __forceinline__ unsigned short f2bf(float x) {
  unsigned u = __float_as_uint(x);
  u += 0x7fffu + ((u >> 16) & 1u);   // RNE
  return (unsigned short)(u >> 16);
}
__device__ __forceinline__ float bf2f(unsigned short b) {
  return __uint_as_float(((unsigned)b) << 16);
}
__device__ __forceinline__ unsigned int packh2(float a, float b) {
  const hh2 p = (hh2){(_Float16)a, (_Float16)b};
  return __builtin_bit_cast(unsigned int, p);
}
__device__ __forceinline__ float fd(unsigned int h2, unsigned int w2, float acc) {
  return __builtin_amdgcn_fdot2(__builtin_bit_cast(hh2, h2),
                                __builtin_bit_cast(hh2, w2), acc, false);
}

// ---------------------------------------------------------------------------
// cvt: Win (fp32) -> bf16, once.
// ---------------------------------------------------------------------------
__global__ void cvt_bf16(const float* __restrict__ src,
                         unsigned short* __restrict__ dst, int n) {
  int i = blockIdx.x * 256 + threadIdx.x;
  if (i < n) dst[i] = f2bf(src[i]);
}

// ---------------------------------------------------------------------------
// cvt_w4: Wh -> W4 (uint4 [16][128]); W4[c*128+f] = pairs {4c+q, 4c+64+q}.
// (r11/r12/r13-verified pairing.)
// ---------------------------------------------------------------------------
__global__ __launch_bounds__(256) void cvt_w4(const float* __restrict__ Wh,
                                              uint4* __restrict__ W4) {
  const int idx = blockIdx.x * 256 + threadIdx.x;   // 2048 total
  const int c = idx >> 7;
  const int f = idx & 127;
  const float* wr = Wh + (size_t)f * EMB;
  uint4 o;
  o.x = packh2(wr[4*c + 0], wr[4*c + 64]);
  o.y = packh2(wr[4*c + 1], wr[4*c + 65]);
  o.z = packh2(wr[4*c + 2], wr[4*c + 66]);
  o.w = packh2(wr[4*c + 3], wr[4*c + 67]);
  W4[idx] = o;
}

// ---------------------------------------------------------------------------
// Phase 1 (verified r2..r13): input projection, paired bf16 output.
// ---------------------------------------------------------------------------
__global__ __launch_bounds__(256) void proj2(
    const int* __restrict__ xidx, const float* __restrict__ emb,
    const unsigned short* __restrict__ Wb, unsigned int* __restrict__ ipP)
{
  const int tid = threadIdx.x;
  const int w   = tid >> 6;
  const int l   = tid & 63;
  const int l15 = l & 15;
  const int lhi = l >> 4;

  short8 bfrag[8][4];
#pragma unroll
  for (int nt = 0; nt < 8; ++nt)
#pragma unroll
    for (int kc = 0; kc < 4; ++kc)
      bfrag[nt][kc] = *(const short8*)(Wb + (nt*16 + l15)*EMB + kc*32 + lhi*8);

#pragma unroll
  for (int t = 0; t < 2; ++t) {
    const int m  = blockIdx.x*8 + w*2 + t;
    const int rb = m * 16;
    const long xe = (long)xidx[rb + l15] * EMB;
    short8 afrag[4];
#pragma unroll
    for (int kc = 0; kc < 4; ++kc) {
      const float4* p = (const float4*)(emb + xe + kc*32 + lhi*8);
      float4 a = p[0], b = p[1];
      short8 fr;
      fr[0]=(short)f2bf(a.x); fr[1]=(short)f2bf(a.y);
      fr[2]=(short)f2bf(a.z); fr[3]=(short)f2bf(a.w);
      fr[4]=(short)f2bf(b.x); fr[5]=(short)f2bf(b.y);
      fr[6]=(short)f2bf(b.z); fr[7]=(short)f2bf(b.w);
      afrag[kc] = fr;
    }
    f32x4 acc[8];
#pragma unroll
    for (int nt = 0; nt < 8; ++nt) acc[nt] = (f32x4)(0.0f);
#pragma unroll
    for (int kc = 0; kc < 4; ++kc)
#pragma unroll
      for (int nt = 0; nt < 8; ++nt)
        acc[nt] = __builtin_amdgcn_mfma_f32_16x16x32_bf16(afrag[kc], bfrag[nt][kc], acc[nt], 0, 0, 0);
#pragma unroll
    for (int nt = 0; nt < 4; ++nt)
#pragma unroll
      for (int j = 0; j < 4; ++j) {
        const unsigned int u = (unsigned)f2bf(acc[nt][j])
                             | ((unsigned)f2bf(acc[nt+4][j]) << 16);
        ipP[(long)(rb + lhi*4 + j)*64 + nt*16 + l15] = u;
      }
  }
}

// ---------------------------------------------------------------------------
// Phase 2: rnn15 — r14's loop-carried weight pin, 32-bit-component form.
// r14 failed to compile: backend rejects TIED 128-bit ("+v"(uint4)) asm
// operands; 32-bit ties are supported (r9 compiled). Pin each quad's four
// dword components instead — same semantics: weights become loop-carried,
// remat of the loads is illegal, allocator (512-reg budget via
// waves_per_eu(1,1), r13-proven) must keep all 128 dwords resident.
// ---------------------------------------------------------------------------
#define PIN4(v) asm volatile("" : "+v"(v.x), "+v"(v.y), "+v"(v.z), "+v"(v.w))

__global__ __attribute__((amdgpu_waves_per_eu(1, 1)))
__launch_bounds__(256) void rnn15(
    const unsigned int* __restrict__ ipP, const uint4* __restrict__ W4,
    const float* __restrict__ bin, const float* __restrict__ bh,
    float* __restrict__ out)
{
  __shared__ unsigned int hb[4][2][64];   // [wave][buf][64 h-pair uints]

  const int tid = threadIdx.x;
  const int w   = tid >> 6;            // wave = local row 0..3
  const int l   = tid & 63;
  const int row = blockIdx.x*4 + w;    // global batch row

  hb[w][0][l] = 0u;                    // h_0 = 0

  // 32 NAMED weight registers (16 chunks x {f=l, f=l+64}), coalesced loads.
#define WLD(i) \
  uint4 wa##i = W4[(i)*128 + l]; \
  uint4 wb##i = W4[(i)*128 + 64 + l];
  WLD(0)  WLD(1)  WLD(2)  WLD(3)  WLD(4)  WLD(5)  WLD(6)  WLD(7)
  WLD(8)  WLD(9)  WLD(10) WLD(11) WLD(12) WLD(13) WLD(14) WLD(15)
#undef WLD

  const float bias0 = bin[l]      + bh[l];
  const float bias1 = bin[l + 64] + bh[l + 64];
  __syncthreads();   // h0 visible (and weight loads drained once)

  // ip stream: uint pair {ip[row][s][l], ip[row][s][l+64]}; prefetch 2 deep
  const unsigned int* ipp = ipP + (size_t)row * SEQ * 64 + l;
  unsigned int ic = ipp[0];
  unsigned int in = ipp[64];

  float hf0 = 0.0f, hf1 = 0.0f;

  for (int s = 0; s < SEQ; ++s) {
    // LOOP-CARRIED PIN (32-bit components): forbids in-loop remat of weights.
    PIN4(wa0);  PIN4(wa1);  PIN4(wa2);  PIN4(wa3);
    PIN4(wa4);  PIN4(wa5);  PIN4(wa6);  PIN4(wa7);
    PIN4(wa8);  PIN4(wa9);  PIN4(wa10); PIN4(wa11);
    PIN4(wa12); PIN4(wa13); PIN4(wa14); PIN4(wa15);
    PIN4(wb0);  PIN4(wb1);  PIN4(wb2);  PIN4(wb3);
    PIN4(wb4);  PIN4(wb5);  PIN4(wb6);  PIN4(wb7);
    PIN4(wb8);  PIN4(wb9);  PIN4(wb10); PIN4(wb11);
    PIN4(wb12); PIN4(wb13); PIN4(wb14); PIN4(wb15);

    const int sp = (s + 2 < SEQ) ? s + 2 : SEQ - 1;
    const unsigned int pn = ipp[(size_t)sp * 64];

    const uint4* th = (const uint4*)&hb[w][s & 1][0];

    float a00 = bias0 + __uint_as_float(ic << 16);
    float a10 = bias1 + __uint_as_float(ic & 0xffff0000u);
    float a01 = 0.0f, a02 = 0.0f, a03 = 0.0f;
    float a11 = 0.0f, a12 = 0.0f, a13 = 0.0f;

    // 16 chunks: broadcast b128 h read + 8 fdot2, named temps (die fast)
#define STEP(i, K) { \
    const uint4 hc = th[i]; \
    a0##K = fd(hc.x, wa##i.x, a0##K); \
    a0##K = fd(hc.y, wa##i.y, a0##K); \
    a0##K = fd(hc.z, wa##i.z, a0##K); \
    a0##K = fd(hc.w, wa##i.w, a0##K); \
    a1##K = fd(hc.x, wb##i.x, a1##K); \
    a1##K = fd(hc.y, wb##i.y, a1##K); \
    a1##K = fd(hc.z, wb##i.z, a1##K); \
    a1##K = fd(hc.w, wb##i.w, a1##K); }
    STEP(0,0)  STEP(1,1)  STEP(2,2)  STEP(3,3)
    STEP(4,0)  STEP(5,1)  STEP(6,2)  STEP(7,3)
    STEP(8,0)  STEP(9,1)  STEP(10,2) STEP(11,3)
    STEP(12,0) STEP(13,1) STEP(14,2) STEP(15,3)
#undef STEP

    const float v0 = (a00 + a01) + (a02 + a03);
    const float v1 = (a10 + a11) + (a12 + a13);

    // tanh (proven path)
    const float e0 = __expf(2.0f * v0);
    hf0 = 1.0f - __fdividef(2.0f, e0 + 1.0f);
    const float e1 = __expf(2.0f * v1);
    hf1 = 1.0f - __fdividef(2.0f, e1 + 1.0f);

    // next h pair; intra-wave DS ordering, no barrier (r8-verified)
    hb[w][(s + 1) & 1][l] = packh2(hf0, hf1);

    ic = in;
    in = pn;
  }

  // L2 normalize: whole row in this wave (2 values/lane)
  float pj = hf0*hf0 + hf1*hf1;
#pragma unroll
  for (int off = 1; off < 64; off <<= 1) pj += __shfl_xor(pj, off, 64);
  const float inv = 1.0f / fmaxf(sqrtf(pj), 1e-12f);
  out[(size_t)row*EMB + l]      = hf0 * inv;
  out[(size_t)row*EMB + 64 + l] = hf1 * inv;
}

// ---------------------------------------------------------------------------
// Fallback (small ws): round-1 VALU recurrence (known-correct, no scratch).
// ---------------------------------------------------------------------------
__global__ __launch_bounds__(512) void rnn_fused(
    const int* __restrict__ xidx, const float* __restrict__ emb,
    const float* __restrict__ Win, const float* __restrict__ bin,
    const float* __restrict__ Wh,  const float* __restrict__ bh,
    float* __restrict__ out)
{
  __shared__ float h_lds[4][EMB];
  __shared__ float part[8][4][EMB];
  __shared__ float emb_lds[2][4][EMB];
  __shared__ int   x_lds[4][SEQ];
  __shared__ float red[8];

  const int t   = threadIdx.x;
  const int f0  = (t & 63) * 2;
  const int eg  = t >> 6;
  const int e0  = eg * 16;
  const int b0  = blockIdx.x * 4;
  const int row = t >> 7;
  const int ff  = t & 127;

  float wh0[16], wh1[16], wi0[16], wi1[16];
  {
    const float* p0 = Wh + f0*EMB + e0;
    const float* p1 = Wh + (f0+1)*EMB + e0;
    const float* q0 = Win + f0*EMB + e0;
    const float* q1 = Win + (f0+1)*EMB + e0;
#pragma unroll
    for (int q = 0; q < 4; ++q) {
      float4 a = ((const float4*)p0)[q];
      wh0[4*q+0]=a.x; wh0[4*q+1]=a.y; wh0[4*q+2]=a.z; wh0[4*q+3]=a.w;
      float4 b = ((const float4*)p1)[q];
      wh1[4*q+0]=b.x; wh1[4*q+1]=b.y; wh1[4*q+2]=b.z; wh1[4*q+3]=b.w;
      float4 c = ((const float4*)q0)[q];
      wi0[4*q+0]=c.x; wi0[4*q+1]=c.y; wi0[4*q+2]=c.z; wi0[4*q+3]=c.w;
      float4 d = ((const float4*)q1)[q];
      wi1[4*q+0]=d.x; wi1[4*q+1]=d.y; wi1[4*q+2]=d.z; wi1[4*q+3]=d.w;
    }
  }
  const float bc = bin[ff] + bh[ff];
  h_lds[row][ff] = 0.0f;
  for (int i = t; i < 4*SEQ; i += 512)
    x_lds[i / SEQ][i % SEQ] = xidx[(b0 + i/SEQ)*SEQ + (i % SEQ)];
  __syncthreads();
  emb_lds[0][row][ff] = emb[(long)x_lds[row][0]*EMB + ff];
  __syncthreads();

  int cur = 0;
  for (int s = 0; s < SEQ; ++s) {
    float nxt = 0.0f;
    if (s + 1 < SEQ) nxt = emb[(long)x_lds[row][s+1]*EMB + ff];
    float pa0[4], pa1[4];
#pragma unroll
    for (int rq = 0; rq < 4; ++rq) { pa0[rq] = 0.0f; pa1[rq] = 0.0f; }
#pragma unroll
    for (int rq = 0; rq < 4; ++rq) {
      const float4* hp  = (const float4*)&h_lds[rq][e0];
      const float4* epv = (const float4*)&emb_lds[cur][rq][e0];
#pragma unroll
      for (int q = 0; q < 4; ++q) {
        float4 hv = hp[q], ev = epv[q];
        pa0[rq] = fmaf(hv.x, wh0[4*q+0], pa0[rq]); pa0[rq] = fmaf(hv.y, wh0[4*q+1], pa0[rq]);
        pa0[rq] = fmaf(hv.z, wh0[4*q+2], pa0[rq]); pa0[rq] = fmaf(hv.w, wh0[4*q+3], pa0[rq]);
        pa1[rq] = fmaf(hv.x, wh1[4*q+0], pa1[rq]); pa1[rq] = fmaf(hv.y, wh1[4*q+1], pa1[rq]);
        pa1[rq] = fmaf(hv.z, wh1[4*q+2], pa1[rq]); pa1[rq] = fmaf(hv.w, wh1[4*q+3], pa1[rq]);
        pa0[rq] = fmaf(ev.x, wi0[4*q+0], pa0[rq]); pa0[rq] = fmaf(ev.y, wi0[4*q+1], pa0[rq]);
        pa0[rq] = fmaf(ev.z, wi0[4*q+2], pa0[rq]); pa0[rq] = fmaf(ev.w, wi0[4*q+3], pa0[rq]);
        pa1[rq] = fmaf(ev.x, wi1[4*q+0], pa1[rq]); pa1[rq] = fmaf(ev.y, wi1[4*q+1], pa1[rq]);
        pa1[rq] = fmaf(ev.z, wi1[4*q+2], pa1[rq]); pa1[rq] = fmaf(ev.w, wi1[4*q+3], pa1[rq]);
      }
    }
#pragma unroll
    for (int rq = 0; rq < 4; ++rq) {
      part[eg][rq][f0]   = pa0[rq];
      part[eg][rq][f0+1] = pa1[rq];
    }
    __syncthreads();
    float acc = bc;
#pragma unroll
    for (int g = 0; g < 8; ++g) acc += part[g][row][ff];
    float hn = tanhf(acc);
    if (s + 1 < SEQ) emb_lds[cur ^ 1][row][ff] = nxt;
    h_lds[row][ff] = hn;
    __syncthreads();
    cur ^= 1;
  }
  float hv = h_lds[row][ff];
  float sq = hv * hv;
#pragma unroll
  for (int off = 32; off > 0; off >>= 1) sq += __shfl_xor(sq, off, 64);
  if ((t & 63) == 0) red[t >> 6] = sq;
  __syncthreads();
  float nrm = sqrtf(red[row*2] + red[row*2 + 1]);
  out[(b0 + row)*EMB + ff] = hv / fmaxf(nrm, 1e-12f);
}

// ---------------------------------------------------------------------------
extern "C" void kernel_launch(void* const* d_in, const int* in_sizes, int n_in,
                              void* d_out, int out_size, void* d_ws, size_t ws_size,
                              hipStream_t stream) {
  const int*   x    = (const int*)  d_in[0];
  const float* emb  = (const float*)d_in[1];
  const float* Win  = (const float*)d_in[2];
  const float* bin  = (const float*)d_in[3];
  const float* Wh   = (const float*)d_in[4];
  const float* bh   = (const float*)d_in[5];
  float* out = (float*)d_out;

  const size_t ip_bytes = (size_t)BATCH * SEQ * 64 * sizeof(unsigned int); // 52.4 MB
  const size_t wb_bytes = (size_t)EMB * EMB * sizeof(unsigned short);      // 32 KB
  const size_t w4_bytes = (size_t)16 * 128 * sizeof(uint4);                // 32 KB
  const size_t need     = ip_bytes + wb_bytes + w4_bytes;
  if (ws_size >= need) {
    unsigned int*   ipP = (unsigned int*)d_ws;
    unsigned short* Wb  = (unsigned short*)((char*)d_ws + ip_bytes);
    uint4*          W4  = (uint4*)((char*)d_ws + ip_bytes + wb_bytes);
    cvt_bf16<<<(EMB*EMB + 255)/256, 256, 0, stream>>>(Win, Wb, EMB*EMB);
    cvt_w4<<<8, 256, 0, stream>>>(Wh, W4);
    proj2<<<(BATCH*SEQ)/128, 256, 0, stream>>>(x, emb, Wb, ipP);
    rnn15<<<BATCH/4, 256, 0, stream>>>(ipP, W4, bin, bh, out);
  } else {
    rnn_fused<<<BATCH/4, 512, 0, stream>>>(x, emb, Win, bin, Wh, bh, out);
  }
}

// Round 16
// 157.616 us; speedup vs baseline: 1.0276x; 1.0276x over previous
//
#include <hip/hip_runtime.h>

#define BATCH 1024
#define SEQ   200
#define EMB   128
#define VOCAB 100000

typedef __attribute__((ext_vector_type(8))) short short8;
typedef __attribute__((ext_vector_type(4))) float f32x4;
typedef _Float16 hh2 __attribute__((ext_vector_type(2)));

__device__ __forceinline__ unsigned short f2bf(float x) {
  unsigned u = __float_as_uint(x);
  u += 0x7fffu + ((u >> 16) & 1u);   // RNE
  return (unsigned short)(u >> 16);
}
__device__ __forceinline__ float bf2f(unsigned short b) {
  return __uint_as_float(((unsigned)b) << 16);
}
__device__ __forceinline__ unsigned int packh2(float a, float b) {
  const hh2 p = (hh2){(_Float16)a, (_Float16)b};
  return __builtin_bit_cast(unsigned int, p);
}
__device__ __forceinline__ float fd(unsigned int h2, unsigned int w2, float acc) {
  return __builtin_amdgcn_fdot2(__builtin_bit_cast(hh2, h2),
                                __builtin_bit_cast(hh2, w2), acc, false);
}

// ---------------------------------------------------------------------------
// cvt: Win (fp32) -> bf16, once.
// ---------------------------------------------------------------------------
__global__ void cvt_bf16(const float* __restrict__ src,
                         unsigned short* __restrict__ dst, int n) {
  int i = blockIdx.x * 256 + threadIdx.x;
  if (i < n) dst[i] = f2bf(src[i]);
}

// ---------------------------------------------------------------------------
// cvt_whq (r10-verified): Wh -> Wq (uint4 [16][128]).
// Wq[c*128 + f] = { pack{Wh[f][8c+2q], Wh[f][8c+2q+1]} : q=0..3 }  (fp16)
// Lane f loads Wq[c*128 + f]: consecutive lanes 16B apart = coalesced.
// ---------------------------------------------------------------------------
__global__ __launch_bounds__(256) void cvt_whq(const float* __restrict__ Wh,
                                               uint4* __restrict__ Wq) {
  const int idx = blockIdx.x * 256 + threadIdx.x;   // 2048 total
  const int c = idx >> 7;
  const int f = idx & 127;
  const float* wr = Wh + (size_t)f * EMB + 8 * c;
  uint4 o;
  o.x = packh2(wr[0], wr[1]);
  o.y = packh2(wr[2], wr[3]);
  o.z = packh2(wr[4], wr[5]);
  o.w = packh2(wr[6], wr[7]);
  Wq[idx] = o;
}

// ---------------------------------------------------------------------------
// Phase 1 (verified r2/r5/r7/r10): ip[r*128+f] = sum_e emb[x[r]][e]*Win[f][e],
// bf16 ushort out. 1600 blocks x 256 thr.
// ---------------------------------------------------------------------------
__global__ __launch_bounds__(256) void proj2(
    const int* __restrict__ xidx, const float* __restrict__ emb,
    const unsigned short* __restrict__ Wb, unsigned short* __restrict__ ip)
{
  const int tid = threadIdx.x;
  const int w   = tid >> 6;
  const int l   = tid & 63;
  const int l15 = l & 15;
  const int lhi = l >> 4;

  short8 bfrag[8][4];
#pragma unroll
  for (int nt = 0; nt < 8; ++nt)
#pragma unroll
    for (int kc = 0; kc < 4; ++kc)
      bfrag[nt][kc] = *(const short8*)(Wb + (nt*16 + l15)*EMB + kc*32 + lhi*8);

#pragma unroll
  for (int t = 0; t < 2; ++t) {
    const int m  = blockIdx.x*8 + w*2 + t;
    const int rb = m * 16;
    const long xe = (long)xidx[rb + l15] * EMB;
    short8 afrag[4];
#pragma unroll
    for (int kc = 0; kc < 4; ++kc) {
      const float4* p = (const float4*)(emb + xe + kc*32 + lhi*8);
      float4 a = p[0], b = p[1];
      short8 fr;
      fr[0]=(short)f2bf(a.x); fr[1]=(short)f2bf(a.y);
      fr[2]=(short)f2bf(a.z); fr[3]=(short)f2bf(a.w);
      fr[4]=(short)f2bf(b.x); fr[5]=(short)f2bf(b.y);
      fr[6]=(short)f2bf(b.z); fr[7]=(short)f2bf(b.w);
      afrag[kc] = fr;
    }
    f32x4 acc[8];
#pragma unroll
    for (int nt = 0; nt < 8; ++nt) acc[nt] = (f32x4)(0.0f);
#pragma unroll
    for (int kc = 0; kc < 4; ++kc)
#pragma unroll
      for (int nt = 0; nt < 8; ++nt)
        acc[nt] = __builtin_amdgcn_mfma_f32_16x16x32_bf16(afrag[kc], bfrag[nt][kc], acc[nt], 0, 0, 0);
#pragma unroll
    for (int nt = 0; nt < 8; ++nt)
#pragma unroll
      for (int j = 0; j < 4; ++j)
        ip[(long)(rb + lhi*4 + j)*EMB + nt*16 + l15] = f2bf(acc[nt][j]);
  }
}

// ---------------------------------------------------------------------------
// Phase 2: rnn16 — rnn10 geometry + r12/r13 residency levers.
// 1024 blocks x 128 thr (2 waves) = 2048 waves = 2/SIMD, all CUs full,
// 4 independent blocks/CU (barrier stalls overlap across blocks).
// Lane owns ONE f = wv*64+l: 64 weight dwords as 16 NAMED uint4 — under the
// empirically-observed ~132-VGPR allocator cap (r13/r15); waves_per_eu(2,2)
// sets the 256-reg budget so ~100 regs stay resident (rnn10's VGPR=44
// failure predates both levers).
// Per step: 1 ip ushort (2-deep prefetch) + 16 broadcast ds_read_b128 +
// 64 fdot2 (4 chains) + tanh + ds_write_b16 + lgkmcnt(0)+s_barrier.
// ---------------------------------------------------------------------------
__global__ __attribute__((amdgpu_waves_per_eu(2, 2)))
__launch_bounds__(128) void rnn16(
    const unsigned short* __restrict__ ip, const uint4* __restrict__ Wq,
    const float* __restrict__ bin, const float* __restrict__ bh,
    float* __restrict__ out)
{
  __shared__ unsigned short hbuf[2][EMB];   // fp16 h, double-buffered
  __shared__ float red[2];

  const int tid = threadIdx.x;
  const int wv  = tid >> 6;            // 0..1 (f-half)
  const int l   = tid & 63;
  const int f   = wv*64 + l;           // owned output
  const int row = blockIdx.x;

  // 16 NAMED weight quads: Wq[c*128+f] = fp16 pairs of Wh[f][8c..8c+7]
#define WLDQ(i) uint4 wq##i = Wq[(i)*128 + f];
  WLDQ(0)  WLDQ(1)  WLDQ(2)  WLDQ(3)  WLDQ(4)  WLDQ(5)  WLDQ(6)  WLDQ(7)
  WLDQ(8)  WLDQ(9)  WLDQ(10) WLDQ(11) WLDQ(12) WLDQ(13) WLDQ(14) WLDQ(15)
#undef WLDQ
  const float bias = bin[f] + bh[f];

  // h_0 = 0 (128 fp16 = 64 uints)
  if (tid < 64) ((unsigned int*)&hbuf[0][0])[tid] = 0u;
  __syncthreads();

  // ip stream: ushort ip[row][s][f]; prefetch 2 deep
  const unsigned short* ipr = ip + (size_t)row * SEQ * EMB + f;
  unsigned short ic = ipr[0];
  unsigned short in = ipr[EMB];

  float hf = 0.0f;

  for (int s = 0; s < SEQ; ++s) {
    const int sp = (s + 2 < SEQ) ? s + 2 : SEQ - 1;
    const unsigned short pn = ipr[(size_t)sp * EMB];

    // broadcast-read full h (256B = 16 x b128, all lanes same addr)
    const uint4* th = (const uint4*)&hbuf[s & 1][0];

    float a0 = bias + bf2f(ic), a1 = 0.0f, a2 = 0.0f, a3 = 0.0f;
#define STEP(i, K) { \
    const uint4 hc = th[i]; \
    a##K = fd(hc.x, wq##i.x, a##K); \
    a##K = fd(hc.y, wq##i.y, a##K); \
    a##K = fd(hc.z, wq##i.z, a##K); \
    a##K = fd(hc.w, wq##i.w, a##K); }
    STEP(0,0)  STEP(1,1)  STEP(2,2)  STEP(3,3)
    STEP(4,0)  STEP(5,1)  STEP(6,2)  STEP(7,3)
    STEP(8,0)  STEP(9,1)  STEP(10,2) STEP(11,3)
    STEP(12,0) STEP(13,1) STEP(14,2) STEP(15,3)
#undef STEP
    const float v = (a0 + a1) + (a2 + a3);

    // tanh (proven path)
    const float e2 = __expf(2.0f * v);
    hf = 1.0f - __fdividef(2.0f, e2 + 1.0f);

    // write h[f] fp16 (64 lanes x b16 = 2-way bank = free)
    hbuf[(s + 1) & 1][f] = __builtin_bit_cast(unsigned short, (_Float16)hf);

    ic = in;
    in = pn;

    // both waves' h visible; ip prefetch stays in flight (no vmcnt)
    asm volatile("s_waitcnt lgkmcnt(0)\n\ts_barrier" ::: "memory");
  }

  // L2 normalize: row split across the 2 waves
  float pj = hf * hf;
#pragma unroll
  for (int off = 1; off < 64; off <<= 1) pj += __shfl_xor(pj, off, 64);
  if (l == 0) red[wv] = pj;
  __syncthreads();
  const float inv = 1.0f / fmaxf(sqrtf(red[0] + red[1]), 1e-12f);
  out[(size_t)row*EMB + f] = hf * inv;
}

// ---------------------------------------------------------------------------
// Fallback (small ws): round-1 VALU recurrence (known-correct, no scratch).
// ---------------------------------------------------------------------------
__global__ __launch_bounds__(512) void rnn_fused(
    const int* __restrict__ xidx, const float* __restrict__ emb,
    const float* __restrict__ Win, const float* __restrict__ bin,
    const float* __restrict__ Wh,  const float* __restrict__ bh,
    float* __restrict__ out)
{
  __shared__ float h_lds[4][EMB];
  __shared__ float part[8][4][EMB];
  __shared__ float emb_lds[2][4][EMB];
  __shared__ int   x_lds[4][SEQ];
  __shared__ float red[8];

  const int t   = threadIdx.x;
  const int f0  = (t & 63) * 2;
  const int eg  = t >> 6;
  const int e0  = eg * 16;
  const int b0  = blockIdx.x * 4;
  const int row = t >> 7;
  const int ff  = t & 127;

  float wh0[16], wh1[16], wi0[16], wi1[16];
  {
    const float* p0 = Wh + f0*EMB + e0;
    const float* p1 = Wh + (f0+1)*EMB + e0;
    const float* q0 = Win + f0*EMB + e0;
    const float* q1 = Win + (f0+1)*EMB + e0;
#pragma unroll
    for (int q = 0; q < 4; ++q) {
      float4 a = ((const float4*)p0)[q];
      wh0[4*q+0]=a.x; wh0[4*q+1]=a.y; wh0[4*q+2]=a.z; wh0[4*q+3]=a.w;
      float4 b = ((const float4*)p1)[q];
      wh1[4*q+0]=b.x; wh1[4*q+1]=b.y; wh1[4*q+2]=b.z; wh1[4*q+3]=b.w;
      float4 c = ((const float4*)q0)[q];
      wi0[4*q+0]=c.x; wi0[4*q+1]=c.y; wi0[4*q+2]=c.z; wi0[4*q+3]=c.w;
      float4 d = ((const float4*)q1)[q];
      wi1[4*q+0]=d.x; wi1[4*q+1]=d.y; wi1[4*q+2]=d.z; wi1[4*q+3]=d.w;
    }
  }
  const float bc = bin[ff] + bh[ff];
  h_lds[row][ff] = 0.0f;
  for (int i = t; i < 4*SEQ; i += 512)
    x_lds[i / SEQ][i % SEQ] = xidx[(b0 + i/SEQ)*SEQ + (i % SEQ)];
  __syncthreads();
  emb_lds[0][row][ff] = emb[(long)x_lds[row][0]*EMB + ff];
  __syncthreads();

  int cur = 0;
  for (int s = 0; s < SEQ; ++s) {
    float nxt = 0.0f;
    if (s + 1 < SEQ) nxt = emb[(long)x_lds[row][s+1]*EMB + ff];
    float pa0[4], pa1[4];
#pragma unroll
    for (int rq = 0; rq < 4; ++rq) { pa0[rq] = 0.0f; pa1[rq] = 0.0f; }
#pragma unroll
    for (int rq = 0; rq < 4; ++rq) {
      const float4* hp  = (const float4*)&h_lds[rq][e0];
      const float4* epv = (const float4*)&emb_lds[cur][rq][e0];
#pragma unroll
      for (int q = 0; q < 4; ++q) {
        float4 hv = hp[q], ev = epv[q];
        pa0[rq] = fmaf(hv.x, wh0[4*q+0], pa0[rq]); pa0[rq] = fmaf(hv.y, wh0[4*q+1], pa0[rq]);
        pa0[rq] = fmaf(hv.z, wh0[4*q+2], pa0[rq]); pa0[rq] = fmaf(hv.w, wh0[4*q+3], pa0[rq]);
        pa1[rq] = fmaf(hv.x, wh1[4*q+0], pa1[rq]); pa1[rq] = fmaf(hv.y, wh1[4*q+1], pa1[rq]);
        pa1[rq] = fmaf(hv.z, wh1[4*q+2], pa1[rq]); pa1[rq] = fmaf(hv.w, wh1[4*q+3], pa1[rq]);
        pa0[rq] = fmaf(ev.x, wi0[4*q+0], pa0[rq]); pa0[rq] = fmaf(ev.y, wi0[4*q+1], pa0[rq]);
        pa0[rq] = fmaf(ev.z, wi0[4*q+2], pa0[rq]); pa0[rq] = fmaf(ev.w, wi0[4*q+3], pa0[rq]);
        pa1[rq] = fmaf(ev.x, wi1[4*q+0], pa1[rq]); pa1[rq] = fmaf(ev.y, wi1[4*q+1], pa1[rq]);
        pa1[rq] = fmaf(ev.z, wi1[4*q+2], pa1[rq]); pa1[rq] = fmaf(ev.w, wi1[4*q+3], pa1[rq]);
      }
    }
#pragma unroll
    for (int rq = 0; rq < 4; ++rq) {
      part[eg][rq][f0]   = pa0[rq];
      part[eg][rq][f0+1] = pa1[rq];
    }
    __syncthreads();
    float acc = bc;
#pragma unroll
    for (int g = 0; g < 8; ++g) acc += part[g][row][ff];
    float hn = tanhf(acc);
    if (s + 1 < SEQ) emb_lds[cur ^ 1][row][ff] = nxt;
    h_lds[row][ff] = hn;
    __syncthreads();
    cur ^= 1;
  }
  float hv = h_lds[row][ff];
  float sq = hv * hv;
#pragma unroll
  for (int off = 32; off > 0; off >>= 1) sq += __shfl_xor(sq, off, 64);
  if ((t & 63) == 0) red[t >> 6] = sq;
  __syncthreads();
  float nrm = sqrtf(red[row*2] + red[row*2 + 1]);
  out[(b0 + row)*EMB + ff] = hv / fmaxf(nrm, 1e-12f);
}

// ---------------------------------------------------------------------------
extern "C" void kernel_launch(void* const* d_in, const int* in_sizes, int n_in,
                              void* d_out, int out_size, void* d_ws, size_t ws_size,
                              hipStream_t stream) {
  const int*   x    = (const int*)  d_in[0];
  const float* emb  = (const float*)d_in[1];
  const float* Win  = (const float*)d_in[2];
  const float* bin  = (const float*)d_in[3];
  const float* Wh   = (const float*)d_in[4];
  const float* bh   = (const float*)d_in[5];
  float* out = (float*)d_out;

  const size_t ip_bytes = (size_t)BATCH * SEQ * EMB * sizeof(unsigned short); // 52.4 MB
  const size_t wb_bytes = (size_t)EMB * EMB * sizeof(unsigned short);         // 32 KB
  const size_t wq_bytes = (size_t)16 * 128 * sizeof(uint4);                   // 32 KB
  const size_t need     = ip_bytes + wb_bytes + wq_bytes;
  if (ws_size >= need) {
    unsigned short* ip = (unsigned short*)d_ws;
    unsigned short* Wb = (unsigned short*)((char*)d_ws + ip_bytes);
    uint4*          Wq = (uint4*)((char*)d_ws + ip_bytes + wb_bytes);
    cvt_bf16<<<(EMB*EMB + 255)/256, 256, 0, stream>>>(Win, Wb, EMB*EMB);
    cvt_whq<<<8, 256, 0, stream>>>(Wh, Wq);
    proj2<<<(BATCH*SEQ)/128, 256, 0, stream>>>(x, emb, Wb, ip);
    rnn16<<<BATCH, 128, 0, stream>>>(ip, Wq, bin, bh, out);
  } else {
    rnn_fused<<<BATCH/4, 512, 0, stream>>>(x, emb, Win, bin, Wh, bh, out);
  }
}

// Round 17
// 142.938 us; speedup vs baseline: 1.1332x; 1.1027x over previous
//
#include <hip/hip_runtime.h>

#define BATCH 1024
#define SEQ   200
#define EMB   128
#define VOCAB 100000

typedef __attribute__((ext_vector_type(8))) short short8;
typedef __attribute__((ext_vector_type(4))) float f32x4;
typedef _Float16 hh2 __attribute__((ext_vector_type(2)));

__device__ __forceinline__ unsigned short f2bf(float x) {
  unsigned u = __float_as_uint(x);
  u += 0x7fffu + ((u >> 16) & 1u);   // RNE
  return (unsigned short)(u >> 16);
}
__device__ __forceinline__ float bf2f(unsigned short b) {
  return __uint_as_float(((unsigned)b) << 16);
}
__device__ __forceinline__ unsigned int packh2(float a, float b) {
  const hh2 p = (hh2){(_Float16)a, (_Float16)b};
  return __builtin_bit_cast(unsigned int, p);
}
__device__ __forceinline__ float fd(unsigned int h2, unsigned int w2, float acc) {
  return __builtin_amdgcn_fdot2(__builtin_bit_cast(hh2, h2),
                                __builtin_bit_cast(hh2, w2), acc, false);
}

// ---------------------------------------------------------------------------
// cvt_all: one launch does BOTH weight conversions.
//   idx <  16384 : Wb[idx] = bf16(Win[idx])
//   idx >= 16384 : j = idx-16384 (0..2047) -> W4[j] (fp16-pair quads of Wh,
//                  pairing {4c+q, 4c+64+q} — r11/r12/r13-verified)
// 18432 items = 72 blocks x 256.
// ---------------------------------------------------------------------------
__global__ __launch_bounds__(256) void cvt_all(
    const float* __restrict__ Win, const float* __restrict__ Wh,
    unsigned short* __restrict__ Wb, uint4* __restrict__ W4) {
  const int idx = blockIdx.x * 256 + threadIdx.x;
  if (idx < 16384) {
    Wb[idx] = f2bf(Win[idx]);
  } else {
    const int j = idx - 16384;       // 0..2047
    const int c = j >> 7;
    const int f = j & 127;
    const float* wr = Wh + (size_t)f * EMB;
    uint4 o;
    o.x = packh2(wr[4*c + 0], wr[4*c + 64]);
    o.y = packh2(wr[4*c + 1], wr[4*c + 65]);
    o.z = packh2(wr[4*c + 2], wr[4*c + 66]);
    o.w = packh2(wr[4*c + 3], wr[4*c + 67]);
    W4[j] = o;
  }
}

// ---------------------------------------------------------------------------
// Phase 1 (verified r2..r16): input projection, paired bf16 output.
// ipP[r*64 + q] = { bf16(ip[r][q]), bf16(ip[r][q+64]) }.
// ---------------------------------------------------------------------------
__global__ __launch_bounds__(256) void proj2(
    const int* __restrict__ xidx, const float* __restrict__ emb,
    const unsigned short* __restrict__ Wb, unsigned int* __restrict__ ipP)
{
  const int tid = threadIdx.x;
  const int w   = tid >> 6;
  const int l   = tid & 63;
  const int l15 = l & 15;
  const int lhi = l >> 4;

  short8 bfrag[8][4];
#pragma unroll
  for (int nt = 0; nt < 8; ++nt)
#pragma unroll
    for (int kc = 0; kc < 4; ++kc)
      bfrag[nt][kc] = *(const short8*)(Wb + (nt*16 + l15)*EMB + kc*32 + lhi*8);

#pragma unroll
  for (int t = 0; t < 2; ++t) {
    const int m  = blockIdx.x*8 + w*2 + t;
    const int rb = m * 16;
    const long xe = (long)xidx[rb + l15] * EMB;
    short8 afrag[4];
#pragma unroll
    for (int kc = 0; kc < 4; ++kc) {
      const float4* p = (const float4*)(emb + xe + kc*32 + lhi*8);
      float4 a = p[0], b = p[1];
      short8 fr;
      fr[0]=(short)f2bf(a.x); fr[1]=(short)f2bf(a.y);
      fr[2]=(short)f2bf(a.z); fr[3]=(short)f2bf(a.w);
      fr[4]=(short)f2bf(b.x); fr[5]=(short)f2bf(b.y);
      fr[6]=(short)f2bf(b.z); fr[7]=(short)f2bf(b.w);
      afrag[kc] = fr;
    }
    f32x4 acc[8];
#pragma unroll
    for (int nt = 0; nt < 8; ++nt) acc[nt] = (f32x4)(0.0f);
#pragma unroll
    for (int kc = 0; kc < 4; ++kc)
#pragma unroll
      for (int nt = 0; nt < 8; ++nt)
        acc[nt] = __builtin_amdgcn_mfma_f32_16x16x32_bf16(afrag[kc], bfrag[nt][kc], acc[nt], 0, 0, 0);
#pragma unroll
    for (int nt = 0; nt < 4; ++nt)
#pragma unroll
      for (int j = 0; j < 4; ++j) {
        const unsigned int u = (unsigned)f2bf(acc[nt][j])
                             | ((unsigned)f2bf(acc[nt+4][j]) << 16);
        ipP[(long)(rb + lhi*4 + j)*64 + nt*16 + l15] = u;
      }
  }
}

// ---------------------------------------------------------------------------
// Phase 2: rnn17 == rnn13 verbatim (best measured: 101.5 us, VGPR 132).
// Wave-per-row, barrier-free; 2 f/lane; fp16-pair h in LDS double-buffer;
// named-scalar weights + waves_per_eu(1,1) (r13-proven partial residency —
// further forcing attempts all regressed: r15 spill, r16 barrier cost).
// ---------------------------------------------------------------------------
__global__ __attribute__((amdgpu_waves_per_eu(1, 1)))
__launch_bounds__(256) void rnn17(
    const unsigned int* __restrict__ ipP, const uint4* __restrict__ W4,
    const float* __restrict__ bin, const float* __restrict__ bh,
    float* __restrict__ out)
{
  __shared__ unsigned int hb[4][2][64];   // [wave][buf][64 h-pair uints]

  const int tid = threadIdx.x;
  const int w   = tid >> 6;            // wave = local row 0..3
  const int l   = tid & 63;
  const int row = blockIdx.x*4 + w;    // global batch row

  hb[w][0][l] = 0u;                    // h_0 = 0

  // 32 NAMED weight registers (16 chunks x {f=l, f=l+64}), coalesced loads.
#define WLD(i) \
  const uint4 wa##i = W4[(i)*128 + l]; \
  const uint4 wb##i = W4[(i)*128 + 64 + l];
  WLD(0)  WLD(1)  WLD(2)  WLD(3)  WLD(4)  WLD(5)  WLD(6)  WLD(7)
  WLD(8)  WLD(9)  WLD(10) WLD(11) WLD(12) WLD(13) WLD(14) WLD(15)
#undef WLD

  const float bias0 = bin[l]      + bh[l];
  const float bias1 = bin[l + 64] + bh[l + 64];
  __syncthreads();   // h0 visible (and weight loads drained once)

  // ip stream: uint pair {ip[row][s][l], ip[row][s][l+64]}; prefetch 2 deep
  const unsigned int* ipp = ipP + (size_t)row * SEQ * 64 + l;
  unsigned int ic = ipp[0];
  unsigned int in = ipp[64];

  float hf0 = 0.0f, hf1 = 0.0f;

  for (int s = 0; s < SEQ; ++s) {
    const int sp = (s + 2 < SEQ) ? s + 2 : SEQ - 1;
    const unsigned int pn = ipp[(size_t)sp * 64];

    const uint4* th = (const uint4*)&hb[w][s & 1][0];

    float a00 = bias0 + __uint_as_float(ic << 16);
    float a10 = bias1 + __uint_as_float(ic & 0xffff0000u);
    float a01 = 0.0f, a02 = 0.0f, a03 = 0.0f;
    float a11 = 0.0f, a12 = 0.0f, a13 = 0.0f;

    // 16 chunks: broadcast b128 h read + 8 fdot2, named temps (die fast)
#define STEP(i, K) { \
    const uint4 hc = th[i]; \
    a0##K = fd(hc.x, wa##i.x, a0##K); \
    a0##K = fd(hc.y, wa##i.y, a0##K); \
    a0##K = fd(hc.z, wa##i.z, a0##K); \
    a0##K = fd(hc.w, wa##i.w, a0##K); \
    a1##K = fd(hc.x, wb##i.x, a1##K); \
    a1##K = fd(hc.y, wb##i.y, a1##K); \
    a1##K = fd(hc.z, wb##i.z, a1##K); \
    a1##K = fd(hc.w, wb##i.w, a1##K); }
    STEP(0,0)  STEP(1,1)  STEP(2,2)  STEP(3,3)
    STEP(4,0)  STEP(5,1)  STEP(6,2)  STEP(7,3)
    STEP(8,0)  STEP(9,1)  STEP(10,2) STEP(11,3)
    STEP(12,0) STEP(13,1) STEP(14,2) STEP(15,3)
#undef STEP

    const float v0 = (a00 + a01) + (a02 + a03);
    const float v1 = (a10 + a11) + (a12 + a13);

    // tanh (proven path)
    const float e0 = __expf(2.0f * v0);
    hf0 = 1.0f - __fdividef(2.0f, e0 + 1.0f);
    const float e1 = __expf(2.0f * v1);
    hf1 = 1.0f - __fdividef(2.0f, e1 + 1.0f);

    // next h pair; intra-wave DS ordering, no barrier (r8-verified)
    hb[w][(s + 1) & 1][l] = packh2(hf0, hf1);

    ic = in;
    in = pn;
  }

  // L2 normalize: whole row in this wave (2 values/lane)
  float pj = hf0*hf0 + hf1*hf1;
#pragma unroll
  for (int off = 1; off < 64; off <<= 1) pj += __shfl_xor(pj, off, 64);
  const float inv = 1.0f / fmaxf(sqrtf(pj), 1e-12f);
  out[(size_t)row*EMB + l]      = hf0 * inv;
  out[(size_t)row*EMB + 64 + l] = hf1 * inv;
}

// ---------------------------------------------------------------------------
// Fallback (small ws): round-1 VALU recurrence (known-correct, no scratch).
// ---------------------------------------------------------------------------
__global__ __launch_bounds__(512) void rnn_fused(
    const int* __restrict__ xidx, const float* __restrict__ emb,
    const float* __restrict__ Win, const float* __restrict__ bin,
    const float* __restrict__ Wh,  const float* __restrict__ bh,
    float* __restrict__ out)
{
  __shared__ float h_lds[4][EMB];
  __shared__ float part[8][4][EMB];
  __shared__ float emb_lds[2][4][EMB];
  __shared__ int   x_lds[4][SEQ];
  __shared__ float red[8];

  const int t   = threadIdx.x;
  const int f0  = (t & 63) * 2;
  const int eg  = t >> 6;
  const int e0  = eg * 16;
  const int b0  = blockIdx.x * 4;
  const int row = t >> 7;
  const int ff  = t & 127;

  float wh0[16], wh1[16], wi0[16], wi1[16];
  {
    const float* p0 = Wh + f0*EMB + e0;
    const float* p1 = Wh + (f0+1)*EMB + e0;
    const float* q0 = Win + f0*EMB + e0;
    const float* q1 = Win + (f0+1)*EMB + e0;
#pragma unroll
    for (int q = 0; q < 4; ++q) {
      float4 a = ((const float4*)p0)[q];
      wh0[4*q+0]=a.x; wh0[4*q+1]=a.y; wh0[4*q+2]=a.z; wh0[4*q+3]=a.w;
      float4 b = ((const float4*)p1)[q];
      wh1[4*q+0]=b.x; wh1[4*q+1]=b.y; wh1[4*q+2]=b.z; wh1[4*q+3]=b.w;
      float4 c = ((const float4*)q0)[q];
      wi0[4*q+0]=c.x; wi0[4*q+1]=c.y; wi0[4*q+2]=c.z; wi0[4*q+3]=c.w;
      float4 d = ((const float4*)q1)[q];
      wi1[4*q+0]=d.x; wi1[4*q+1]=d.y; wi1[4*q+2]=d.z; wi1[4*q+3]=d.w;
    }
  }
  const float bc = bin[ff] + bh[ff];
  h_lds[row][ff] = 0.0f;
  for (int i = t; i < 4*SEQ; i += 512)
    x_lds[i / SEQ][i % SEQ] = xidx[(b0 + i/SEQ)*SEQ + (i % SEQ)];
  __syncthreads();
  emb_lds[0][row][ff] = emb[(long)x_lds[row][0]*EMB + ff];
  __syncthreads();

  int cur = 0;
  for (int s = 0; s < SEQ; ++s) {
    float nxt = 0.0f;
    if (s + 1 < SEQ) nxt = emb[(long)x_lds[row][s+1]*EMB + ff];
    float pa0[4], pa1[4];
#pragma unroll
    for (int rq = 0; rq < 4; ++rq) { pa0[rq] = 0.0f; pa1[rq] = 0.0f; }
#pragma unroll
    for (int rq = 0; rq < 4; ++rq) {
      const float4* hp  = (const float4*)&h_lds[rq][e0];
      const float4* epv = (const float4*)&emb_lds[cur][rq][e0];
#pragma unroll
      for (int q = 0; q < 4; ++q) {
        float4 hv = hp[q], ev = epv[q];
        pa0[rq] = fmaf(hv.x, wh0[4*q+0], pa0[rq]); pa0[rq] = fmaf(hv.y, wh0[4*q+1], pa0[rq]);
        pa0[rq] = fmaf(hv.z, wh0[4*q+2], pa0[rq]); pa0[rq] = fmaf(hv.w, wh0[4*q+3], pa0[rq]);
        pa1[rq] = fmaf(hv.x, wh1[4*q+0], pa1[rq]); pa1[rq] = fmaf(hv.y, wh1[4*q+1], pa1[rq]);
        pa1[rq] = fmaf(hv.z, wh1[4*q+2], pa1[rq]); pa1[rq] = fmaf(hv.w, wh1[4*q+3], pa1[rq]);
        pa0[rq] = fmaf(ev.x, wi0[4*q+0], pa0[rq]); pa0[rq] = fmaf(ev.y, wi0[4*q+1], pa0[rq]);
        pa0[rq] = fmaf(ev.z, wi0[4*q+2], pa0[rq]); pa0[rq] = fmaf(ev.w, wi0[4*q+3], pa0[rq]);
        pa1[rq] = fmaf(ev.x, wi1[4*q+0], pa1[rq]); pa1[rq] = fmaf(ev.y, wi1[4*q+1], pa1[rq]);
        pa1[rq] = fmaf(ev.z, wi1[4*q+2], pa1[rq]); pa1[rq] = fmaf(ev.w, wi1[4*q+3], pa1[rq]);
      }
    }
#pragma unroll
    for (int rq = 0; rq < 4; ++rq) {
      part[eg][rq][f0]   = pa0[rq];
      part[eg][rq][f0+1] = pa1[rq];
    }
    __syncthreads();
    float acc = bc;
#pragma unroll
    for (int g = 0; g < 8; ++g) acc += part[g][row][ff];
    float hn = tanhf(acc);
    if (s + 1 < SEQ) emb_lds[cur ^ 1][row][ff] = nxt;
    h_lds[row][ff] = hn;
    __syncthreads();
    cur ^= 1;
  }
  float hv = h_lds[row][ff];
  float sq = hv * hv;
#pragma unroll
  for (int off = 32; off > 0; off >>= 1) sq += __shfl_xor(sq, off, 64);
  if ((t & 63) == 0) red[t >> 6] = sq;
  __syncthreads();
  float nrm = sqrtf(red[row*2] + red[row*2 + 1]);
  out[(b0 + row)*EMB + ff] = hv / fmaxf(nrm, 1e-12f);
}

// ---------------------------------------------------------------------------
extern "C" void kernel_launch(void* const* d_in, const int* in_sizes, int n_in,
                              void* d_out, int out_size, void* d_ws, size_t ws_size,
                              hipStream_t stream) {
  const int*   x    = (const int*)  d_in[0];
  const float* emb  = (const float*)d_in[1];
  const float* Win  = (const float*)d_in[2];
  const float* bin  = (const float*)d_in[3];
  const float* Wh   = (const float*)d_in[4];
  const float* bh   = (const float*)d_in[5];
  float* out = (float*)d_out;

  const size_t ip_bytes = (size_t)BATCH * SEQ * 64 * sizeof(unsigned int); // 52.4 MB
  const size_t wb_bytes = (size_t)EMB * EMB * sizeof(unsigned short);      // 32 KB
  const size_t w4_bytes = (size_t)16 * 128 * sizeof(uint4);                // 32 KB
  const size_t need     = ip_bytes + wb_bytes + w4_bytes;
  if (ws_size >= need) {
    unsigned int*   ipP = (unsigned int*)d_ws;
    unsigned short* Wb  = (unsigned short*)((char*)d_ws + ip_bytes);
    uint4*          W4  = (uint4*)((char*)d_ws + ip_bytes + wb_bytes);
    cvt_all<<<72, 256, 0, stream>>>(Win, Wh, Wb, W4);
    proj2<<<(BATCH*SEQ)/128, 256, 0, stream>>>(x, emb, Wb, ipP);
    rnn17<<<BATCH/4, 256, 0, stream>>>(ipP, W4, bin, bh, out);
  } else {
    rnn_fused<<<BATCH/4, 512, 0, stream>>>(x, emb, Win, bin, Wh, bh, out);
  }
}